// Round 7
// baseline (273.251 us; speedup 1.0000x reference)
//
#include <hip/hip_runtime.h>
#include <hip/hip_bf16.h>

#define NN 100000
#define NE 1600000

typedef __bf16 bf16x8 __attribute__((ext_vector_type(8)));
typedef float  f32x4  __attribute__((ext_vector_type(4)));

// ---------------------------------------------------------------------------
// Fused prep: blocks [0,6250) build CSR row_ptr from sorted edge_row;
// blocks [6250,6346) pack W0/W1 to bf16 [n][k] (B-operand layout).
// ---------------------------------------------------------------------------
__global__ __launch_bounds__(256) void prep_kernel(const int* __restrict__ row,
                                                   int* __restrict__ row_ptr,
                                                   const float* __restrict__ W0,
                                                   const float* __restrict__ W1,
                                                   __hip_bfloat16* __restrict__ Wt0,
                                                   __hip_bfloat16* __restrict__ Wt1) {
    int b = blockIdx.x;
    if (b < NE / 256) {
        int e = b * 256 + threadIdx.x;
        int r  = row[e];
        int rp = (e == 0) ? -1 : row[e - 1];
        for (int i = rp + 1; i <= r; ++i) row_ptr[i] = e;
        if (e == NE - 1) {
            for (int i = r + 1; i <= NN; ++i) row_ptr[i] = NE;
        }
    } else {
        int idx = (b - NE / 256) * 256 + threadIdx.x;
        if (idx < 128 * 128) {
            int n = idx >> 7, k = idx & 127;
            Wt0[idx] = __float2bfloat16(W0[(size_t)k * 128 + n]);
        } else {
            int r2 = idx - 128 * 128;          // < 64*128 by grid size
            int n = r2 >> 7, k = r2 & 127;
            Wt1[r2] = __float2bfloat16(W1[(size_t)k * 64 + n]);
        }
    }
}

__device__ inline float deg_scale(const int* __restrict__ row_ptr, int i) {
    int dg = row_ptr[i + 1] - row_ptr[i];
    return (dg > 0) ? rsqrtf((float)dg) : 0.0f;
}

// ---------------------------------------------------------------------------
// MFMA bf16 GEMM: out[M,NO] = dinv[r] * (X[M,128] @ Wt^T + bias), bf16 out.
// BM=128 rows/block, 512 threads (8 waves). A tile staged in 32KB swizzled
// LDS (4 blocks/CU); B-fragments read directly from global Wt (32/16KB,
// L1/L2-resident) -- no Ws stage, no second barrier.
// Epilogue: C-frags -> wave-local LDS rows (no barrier) -> coalesced uint4.
// Fragment layouts (m89-verified): A[m=lane&15][k=quad*8+j],
// B[n=lane&15][k=quad*8+j], C[row=quad*4+reg][col=lane&15].
// ---------------------------------------------------------------------------
template <int NO, typename InT>
__global__ __launch_bounds__(512) void gemm_mfma(const InT* __restrict__ X,
                                                 const __hip_bfloat16* __restrict__ Wt,
                                                 const float* __restrict__ bias,
                                                 const int* __restrict__ row_ptr,
                                                 __hip_bfloat16* __restrict__ out, int M) {
    constexpr int NT = NO / 16;
    __shared__ unsigned short As[128 * 128];

    const int t = threadIdx.x;
    const int w = t >> 6, lane = t & 63;
    const int l15 = lane & 15, quad = lane >> 4;
    const int rbase = blockIdx.x * 128;

    // stage A tile (128 x 128) -> As (bf16, XOR-swizzled granules)
    if constexpr (sizeof(InT) == 4) {
        for (int i = t; i < 4096; i += 512) {        // 128 rows x 32 float4
            int r = i >> 5, c2 = i & 31;             // c2: float4 chunk (4 shorts)
            float4 xv = make_float4(0.f, 0.f, 0.f, 0.f);
            if (rbase + r < M) xv = ((const float4*)X)[(size_t)rbase * 32 + i];
            union { __hip_bfloat162 h; unsigned int u; } p0, p1;
            p0.h = __float22bfloat162_rn(make_float2(xv.x, xv.y));
            p1.h = __float22bfloat162_rn(make_float2(xv.z, xv.w));
            int phys = ((c2 >> 1) ^ (r & 7));
            *(uint2*)&As[r * 128 + (phys << 3) + ((c2 & 1) << 2)] = make_uint2(p0.u, p1.u);
        }
    } else {
        for (int i = t; i < 2048; i += 512) {        // 128 rows x 16 uint4
            int r = i >> 4, g = i & 15;
            uint4 v = make_uint4(0u, 0u, 0u, 0u);
            if (rbase + r < M) v = ((const uint4*)X)[(size_t)rbase * 16 + i];
            *(uint4*)&As[r * 128 + ((g ^ (r & 7)) << 3)] = v;
        }
    }
    __syncthreads();

    f32x4 acc[NT];
#pragma unroll
    for (int nt = 0; nt < NT; ++nt) {
        float bv = bias[nt * 16 + l15];
        acc[nt][0] = bv; acc[nt][1] = bv; acc[nt][2] = bv; acc[nt][3] = bv;
    }

    const int arow = w * 16 + l15;
    const int asw  = arow & 7;
#pragma unroll 1
    for (int kc = 0; kc < 4; ++kc) {
        bf16x8 af = *(const bf16x8*)&As[arow * 128 + (((kc * 4 + quad) ^ asw) << 3)];
#pragma unroll
        for (int nt = 0; nt < NT; ++nt) {
            bf16x8 bfr = *(const bf16x8*)&Wt[(size_t)(nt * 16 + l15) * 128 + kc * 32 + quad * 8];
            acc[nt] = __builtin_amdgcn_mfma_f32_16x16x32_bf16(af, bfr, acc[nt], 0, 0, 0);
        }
    }

    // epilogue: C -> wave-local LDS rows (swizzled bf16), then coalesced stores
    __hip_bfloat16* Cs = (__hip_bfloat16*)As;
#pragma unroll
    for (int r4 = 0; r4 < 4; ++r4) {
        int lrow = w * 16 + quad * 4 + r4;
        int grow = rbase + lrow;
        float sc = (grow < M) ? deg_scale(row_ptr, grow) : 0.f;
#pragma unroll
        for (int nt = 0; nt < NT; ++nt) {
            int ct = nt * 16 + l15;
            Cs[lrow * 128 + ((((ct >> 3) ^ (lrow & 7)) << 3)) + (ct & 7)] =
                __float2bfloat16(acc[nt][r4] * sc);
        }
    }
    // wave-local RAW on LDS (each wave reads only the rows it wrote): no barrier
    constexpr int RJ  = NO / 8;           // uint4 granules per row
    constexpr int CNT = (16 * RJ) / 64;   // per-lane store count
#pragma unroll
    for (int k = 0; k < CNT; ++k) {
        int idx = k * 64 + lane;
        int lr16 = idx / RJ, j = idx % RJ;
        int lrow = w * 16 + lr16;
        int grow = rbase + lrow;
        if (grow < M) {
            uint4 v = *(const uint4*)&Cs[lrow * 128 + ((j ^ (lrow & 7)) << 3)];
            *(uint4*)&out[(size_t)grow * NO + (j << 3)] = v;
        }
    }
}

// ---------------------------------------------------------------------------
// SpMM (CSR, wave-per-row), F=128, bf16 H (pre-scaled by dinv[col]), relu,
// bf16 out. Wave-uniform row -> col via s_load; 16 outstanding gathers.
// ---------------------------------------------------------------------------
__global__ __launch_bounds__(256) void spmm_relu_128(const int* __restrict__ row_ptr,
                                                     const int* __restrict__ col,
                                                     const unsigned int* __restrict__ H, // bf16x2
                                                     __hip_bfloat16* __restrict__ out, int N) {
    const int lane = threadIdx.x & 63;
    int i = __builtin_amdgcn_readfirstlane(blockIdx.x * 4 + (threadIdx.x >> 6));
    if (i >= N) return;
    const int e0 = __builtin_amdgcn_readfirstlane(row_ptr[i]);
    const int e1 = __builtin_amdgcn_readfirstlane(row_ptr[i + 1]);
    const int dg = e1 - e0;
    const float di = (dg > 0) ? rsqrtf((float)dg) : 0.0f;
    float accx = 0.f, accy = 0.f;
    int e = e0;
    for (; e + 16 <= e1; e += 16) {
        unsigned int u[16];
#pragma unroll
        for (int j = 0; j < 16; ++j) {
            int c = __builtin_amdgcn_readfirstlane(col[e + j]);
            u[j] = H[(size_t)c * 64 + lane];
        }
#pragma unroll
        for (int j = 0; j < 16; ++j) {
            accx += __uint_as_float(u[j] << 16);
            accy += __uint_as_float(u[j] & 0xffff0000u);
        }
    }
    for (; e + 8 <= e1; e += 8) {
        unsigned int u[8];
#pragma unroll
        for (int j = 0; j < 8; ++j) {
            int c = __builtin_amdgcn_readfirstlane(col[e + j]);
            u[j] = H[(size_t)c * 64 + lane];
        }
#pragma unroll
        for (int j = 0; j < 8; ++j) {
            accx += __uint_as_float(u[j] << 16);
            accy += __uint_as_float(u[j] & 0xffff0000u);
        }
    }
    for (; e < e1; ++e) {
        int c = __builtin_amdgcn_readfirstlane(col[e]);
        unsigned int u = H[(size_t)c * 64 + lane];
        accx += __uint_as_float(u << 16);
        accy += __uint_as_float(u & 0xffff0000u);
    }
    accx = fmaxf(accx * di, 0.f);
    accy = fmaxf(accy * di, 0.f);
    *(__hip_bfloat162*)&out[(size_t)i * 128 + 2 * lane] =
        __float22bfloat162_rn(make_float2(accx, accy));
}

// ---------------------------------------------------------------------------
// SpMM (CSR, wave-per-row), F=64, bf16 H (pre-scaled), fused log_softmax.
// ---------------------------------------------------------------------------
__global__ __launch_bounds__(256) void spmm_logsoftmax_64(const int* __restrict__ row_ptr,
                                                          const int* __restrict__ col,
                                                          const unsigned short* __restrict__ H, // bf16
                                                          float* __restrict__ out, int N) {
    const int lane = threadIdx.x & 63;
    int i = __builtin_amdgcn_readfirstlane(blockIdx.x * 4 + (threadIdx.x >> 6));
    if (i >= N) return;
    const int e0 = __builtin_amdgcn_readfirstlane(row_ptr[i]);
    const int e1 = __builtin_amdgcn_readfirstlane(row_ptr[i + 1]);
    const int dg = e1 - e0;
    const float di = (dg > 0) ? rsqrtf((float)dg) : 0.0f;
    float acc = 0.f;
    int e = e0;
    for (; e + 16 <= e1; e += 16) {
        unsigned short u[16];
#pragma unroll
        for (int j = 0; j < 16; ++j) {
            int c = __builtin_amdgcn_readfirstlane(col[e + j]);
            u[j] = H[(size_t)c * 64 + lane];
        }
#pragma unroll
        for (int j = 0; j < 16; ++j)
            acc += __uint_as_float((unsigned int)u[j] << 16);
    }
    for (; e + 8 <= e1; e += 8) {
        unsigned short u[8];
#pragma unroll
        for (int j = 0; j < 8; ++j) {
            int c = __builtin_amdgcn_readfirstlane(col[e + j]);
            u[j] = H[(size_t)c * 64 + lane];
        }
#pragma unroll
        for (int j = 0; j < 8; ++j)
            acc += __uint_as_float((unsigned int)u[j] << 16);
    }
    for (; e < e1; ++e) {
        int c = __builtin_amdgcn_readfirstlane(col[e]);
        acc += __uint_as_float((unsigned int)H[(size_t)c * 64 + lane] << 16);
    }
    acc *= di;
    float m = acc;
#pragma unroll
    for (int off = 32; off > 0; off >>= 1)
        m = fmaxf(m, __shfl_xor(m, off, 64));
    float ex = __expf(acc - m);
    float s = ex;
#pragma unroll
    for (int off = 32; off > 0; off >>= 1)
        s += __shfl_xor(s, off, 64);
    out[(size_t)i * 64 + lane] = acc - m - __logf(s);
}

// ---------------------------------------------------------------------------
extern "C" void kernel_launch(void* const* d_in, const int* in_sizes, int n_in,
                              void* d_out, int out_size, void* d_ws, size_t ws_size,
                              hipStream_t stream) {
    const float* x    = (const float*)d_in[0];
    const int*   erow = (const int*)d_in[1];
    const int*   ecol = (const int*)d_in[2];
    const float* W0   = (const float*)d_in[3];
    const float* b0   = (const float*)d_in[4];
    const float* W1   = (const float*)d_in[5];
    const float* b1   = (const float*)d_in[6];
    float* out = (float*)d_out;

    char* ws = (char*)d_ws;
    // layout (bytes):
    //   [0, 512K)            row_ptr (100001 int)
    //   [1M, +25.6M)         h0b  bf16 100000*128   (pre-scaled by dinv[row])
    //   [27M, +25.6M)        h1b  bf16 100000*128
    //   [53M, +12.8M)        h2b  bf16 100000*64    (pre-scaled by dinv[row])
    //   [66M, +32K)          Wt0  bf16 128*128 (as [n][k])
    //   [66.1M, +16K)        Wt1  bf16 64*128  (as [n][k])
    int*             row_ptr = (int*)ws;
    __hip_bfloat16*  h0b     = (__hip_bfloat16*)(ws + (1u << 20));
    __hip_bfloat16*  h1b     = (__hip_bfloat16*)(ws + 27000000u);
    __hip_bfloat16*  h2b     = (__hip_bfloat16*)(ws + 53000000u);
    __hip_bfloat16*  Wt0     = (__hip_bfloat16*)(ws + 66000000u);
    __hip_bfloat16*  Wt1     = (__hip_bfloat16*)(ws + 66100000u);

    // 1. prep: row_ptr + packed weights (one launch)
    prep_kernel<<<NE / 256 + 96, 256, 0, stream>>>(erow, row_ptr, W0, W1, Wt0, Wt1);
    // 2. h0b = bf16(dinv[r] * (x @ W0 + b0))        [MFMA, BM=128, no Ws stage]
    gemm_mfma<128, float><<<(NN + 127) / 128, 512, 0, stream>>>(x, Wt0, b0, row_ptr, h0b, NN);
    // 3. h1b = bf16(relu(di * sum H[col]))
    spmm_relu_128<<<(NN + 3) / 4, 256, 0, stream>>>(row_ptr, ecol,
                                                    (const unsigned int*)h0b, h1b, NN);
    // 4. h2b = bf16(dinv[r] * (h1b @ W1 + b1))      [MFMA]
    gemm_mfma<64, __hip_bfloat16><<<(NN + 127) / 128, 512, 0, stream>>>(h1b, Wt1, b1, row_ptr, h2b, NN);
    // 5. out = log_softmax(di * sum H[col])
    spmm_logsoftmax_64<<<(NN + 3) / 4, 256, 0, stream>>>(row_ptr, ecol,
                                                         (const unsigned short*)h2b, out, NN);
}

// Round 8
// 239.177 us; speedup vs baseline: 1.1425x; 1.1425x over previous
//
#include <hip/hip_runtime.h>
#include <hip/hip_bf16.h>

#define NN 100000
#define NE 1600000

typedef __bf16 bf16x8 __attribute__((ext_vector_type(8)));
typedef float  f32x4  __attribute__((ext_vector_type(4)));

// ---------------------------------------------------------------------------
// Fused prep: blocks [0,6250) build CSR row_ptr from sorted edge_row;
// blocks [6250,6346) pack W0/W1 to bf16 [n][k] (B-operand layout).
// ---------------------------------------------------------------------------
__global__ __launch_bounds__(256) void prep_kernel(const int* __restrict__ row,
                                                   int* __restrict__ row_ptr,
                                                   const float* __restrict__ W0,
                                                   const float* __restrict__ W1,
                                                   __hip_bfloat16* __restrict__ Wt0,
                                                   __hip_bfloat16* __restrict__ Wt1) {
    int b = blockIdx.x;
    if (b < NE / 256) {
        int e = b * 256 + threadIdx.x;
        int r  = row[e];
        int rp = (e == 0) ? -1 : row[e - 1];
        for (int i = rp + 1; i <= r; ++i) row_ptr[i] = e;
        if (e == NE - 1) {
            for (int i = r + 1; i <= NN; ++i) row_ptr[i] = NE;
        }
    } else {
        int idx = (b - NE / 256) * 256 + threadIdx.x;
        if (idx < 128 * 128) {
            int n = idx >> 7, k = idx & 127;
            Wt0[idx] = __float2bfloat16(W0[(size_t)k * 128 + n]);
        } else {
            int r2 = idx - 128 * 128;          // < 64*128 by grid size
            int n = r2 >> 7, k = r2 & 127;
            Wt1[r2] = __float2bfloat16(W1[(size_t)k * 64 + n]);
        }
    }
}

__device__ inline float deg_scale(const int* __restrict__ row_ptr, int i) {
    int dg = row_ptr[i + 1] - row_ptr[i];
    return (dg > 0) ? rsqrtf((float)dg) : 0.0f;
}

// ---------------------------------------------------------------------------
// MFMA bf16 GEMM: out[M,NO] = dinv[r] * (X[M,128] @ Wt^T + bias), bf16 out.
// 512 threads / 8 waves, BM=128 rows (16 per wave). A-fragments are loaded
// DIRECTLY from global per-lane (A[m=lane&15][k=quad*8+j] => one contiguous
// 32B fp32 / 16B bf16 chunk per kc, coalesced across the 16 rows) -- no A
// staging, no barrier on the A path. W stays in XOR-swizzled LDS (reused by
// all waves). Epilogue: C-frags -> wave-local LDS rows -> coalesced uint4.
// Fragment layouts (m89-verified): A[m=lane&15][k=quad*8+j],
// B[n=lane&15][k=quad*8+j], C[row=quad*4+reg][col=lane&15].
// ---------------------------------------------------------------------------
template <int NO, typename InT>
__global__ __launch_bounds__(512) void gemm_mfma(const InT* __restrict__ X,
                                                 const __hip_bfloat16* __restrict__ Wt,
                                                 const float* __restrict__ bias,
                                                 const int* __restrict__ row_ptr,
                                                 __hip_bfloat16* __restrict__ out, int M) {
    constexpr int NT = NO / 16;
    __shared__ unsigned short Ws[NO * 128];
    __shared__ unsigned short Cs[128 * 128];   // epilogue transpose buffer

    const int t = threadIdx.x;
    const int w = t >> 6, lane = t & 63;
    const int l15 = lane & 15, quad = lane >> 4;
    const int rbase = blockIdx.x * 128;

    // stage Wt (NO x 128 bf16) -> Ws, XOR-swizzled granules
    for (int i = t; i < NO * 16; i += 512) {
        int n = i >> 4, g = i & 15;
        *(uint4*)&Ws[n * 128 + ((g ^ (n & 7)) << 3)] = ((const uint4*)Wt)[i];
    }
    __syncthreads();

    // A row for this lane (clamped; garbage rows only corrupt masked C rows)
    const int arow_g = rbase + w * 16 + l15;
    const int arow   = (arow_g < M) ? arow_g : (M - 1);

    // load A fragments for all 4 kc chunks up front (coalesced, in-flight)
    bf16x8 af[4];
    if constexpr (sizeof(InT) == 4) {
        float4 lo[4], hi[4];
#pragma unroll
        for (int kc = 0; kc < 4; ++kc) {
            const float4* src = (const float4*)&X[(size_t)arow * 128 + kc * 32 + quad * 8];
            lo[kc] = src[0];
            hi[kc] = src[1];
        }
#pragma unroll
        for (int kc = 0; kc < 4; ++kc) {
            union { bf16x8 v; __hip_bfloat162 h[4]; } u;
            u.h[0] = __float22bfloat162_rn(make_float2(lo[kc].x, lo[kc].y));
            u.h[1] = __float22bfloat162_rn(make_float2(lo[kc].z, lo[kc].w));
            u.h[2] = __float22bfloat162_rn(make_float2(hi[kc].x, hi[kc].y));
            u.h[3] = __float22bfloat162_rn(make_float2(hi[kc].z, hi[kc].w));
            af[kc] = u.v;
        }
    } else {
        union { bf16x8 v; uint4 q; } u[4];
#pragma unroll
        for (int kc = 0; kc < 4; ++kc)
            u[kc].q = *(const uint4*)&X[(size_t)arow * 128 + kc * 32 + quad * 8];
#pragma unroll
        for (int kc = 0; kc < 4; ++kc) af[kc] = u[kc].v;
    }

    f32x4 acc[NT];
#pragma unroll
    for (int nt = 0; nt < NT; ++nt) {
        float bv = bias[nt * 16 + l15];
        acc[nt][0] = bv; acc[nt][1] = bv; acc[nt][2] = bv; acc[nt][3] = bv;
    }

#pragma unroll
    for (int kc = 0; kc < 4; ++kc) {
#pragma unroll
        for (int nt = 0; nt < NT; ++nt) {
            int brow = nt * 16 + l15;
            bf16x8 bfr = *(const bf16x8*)&Ws[brow * 128 + (((kc * 4 + quad) ^ (brow & 7)) << 3)];
            acc[nt] = __builtin_amdgcn_mfma_f32_16x16x32_bf16(af[kc], bfr, acc[nt], 0, 0, 0);
        }
    }

    // epilogue: C -> wave-local LDS rows (swizzled bf16), then coalesced stores
    __hip_bfloat16* Cp = (__hip_bfloat16*)Cs;
#pragma unroll
    for (int r4 = 0; r4 < 4; ++r4) {
        int lrow = w * 16 + quad * 4 + r4;
        int grow = rbase + lrow;
        float sc = (grow < M) ? deg_scale(row_ptr, grow) : 0.f;
#pragma unroll
        for (int nt = 0; nt < NT; ++nt) {
            int ct = nt * 16 + l15;
            Cp[lrow * 128 + ((((ct >> 3) ^ (lrow & 7)) << 3)) + (ct & 7)] =
                __float2bfloat16(acc[nt][r4] * sc);
        }
    }
    // wave-local RAW on LDS (each wave reads only the rows it wrote): no barrier
    constexpr int RJ  = NO / 8;           // uint4 granules per row
    constexpr int CNT = (16 * RJ) / 64;   // per-lane store count
#pragma unroll
    for (int k = 0; k < CNT; ++k) {
        int idx = k * 64 + lane;
        int lr16 = idx / RJ, j = idx % RJ;
        int lrow = w * 16 + lr16;
        int grow = rbase + lrow;
        if (grow < M) {
            uint4 v = *(const uint4*)&Cp[lrow * 128 + ((j ^ (lrow & 7)) << 3)];
            *(uint4*)&out[(size_t)grow * NO + (j << 3)] = v;
        }
    }
}

// ---------------------------------------------------------------------------
// SpMM (CSR, wave-per-row), F=128, bf16 H (pre-scaled by dinv[col]), relu,
// bf16 out. Wave-uniform row -> col via s_load; 16 outstanding gathers.
// ---------------------------------------------------------------------------
__global__ __launch_bounds__(256) void spmm_relu_128(const int* __restrict__ row_ptr,
                                                     const int* __restrict__ col,
                                                     const unsigned int* __restrict__ H, // bf16x2
                                                     __hip_bfloat16* __restrict__ out, int N) {
    const int lane = threadIdx.x & 63;
    int i = __builtin_amdgcn_readfirstlane(blockIdx.x * 4 + (threadIdx.x >> 6));
    if (i >= N) return;
    const int e0 = __builtin_amdgcn_readfirstlane(row_ptr[i]);
    const int e1 = __builtin_amdgcn_readfirstlane(row_ptr[i + 1]);
    const int dg = e1 - e0;
    const float di = (dg > 0) ? rsqrtf((float)dg) : 0.0f;
    float accx = 0.f, accy = 0.f;
    int e = e0;
    for (; e + 16 <= e1; e += 16) {
        unsigned int u[16];
#pragma unroll
        for (int j = 0; j < 16; ++j) {
            int c = __builtin_amdgcn_readfirstlane(col[e + j]);
            u[j] = H[(size_t)c * 64 + lane];
        }
#pragma unroll
        for (int j = 0; j < 16; ++j) {
            accx += __uint_as_float(u[j] << 16);
            accy += __uint_as_float(u[j] & 0xffff0000u);
        }
    }
    for (; e + 8 <= e1; e += 8) {
        unsigned int u[8];
#pragma unroll
        for (int j = 0; j < 8; ++j) {
            int c = __builtin_amdgcn_readfirstlane(col[e + j]);
            u[j] = H[(size_t)c * 64 + lane];
        }
#pragma unroll
        for (int j = 0; j < 8; ++j) {
            accx += __uint_as_float(u[j] << 16);
            accy += __uint_as_float(u[j] & 0xffff0000u);
        }
    }
    for (; e < e1; ++e) {
        int c = __builtin_amdgcn_readfirstlane(col[e]);
        unsigned int u = H[(size_t)c * 64 + lane];
        accx += __uint_as_float(u << 16);
        accy += __uint_as_float(u & 0xffff0000u);
    }
    accx = fmaxf(accx * di, 0.f);
    accy = fmaxf(accy * di, 0.f);
    *(__hip_bfloat162*)&out[(size_t)i * 128 + 2 * lane] =
        __float22bfloat162_rn(make_float2(accx, accy));
}

// ---------------------------------------------------------------------------
// SpMM (CSR, wave-per-row), F=64, bf16 H (pre-scaled), fused log_softmax.
// ---------------------------------------------------------------------------
__global__ __launch_bounds__(256) void spmm_logsoftmax_64(const int* __restrict__ row_ptr,
                                                          const int* __restrict__ col,
                                                          const unsigned short* __restrict__ H, // bf16
                                                          float* __restrict__ out, int N) {
    const int lane = threadIdx.x & 63;
    int i = __builtin_amdgcn_readfirstlane(blockIdx.x * 4 + (threadIdx.x >> 6));
    if (i >= N) return;
    const int e0 = __builtin_amdgcn_readfirstlane(row_ptr[i]);
    const int e1 = __builtin_amdgcn_readfirstlane(row_ptr[i + 1]);
    const int dg = e1 - e0;
    const float di = (dg > 0) ? rsqrtf((float)dg) : 0.0f;
    float acc = 0.f;
    int e = e0;
    for (; e + 16 <= e1; e += 16) {
        unsigned short u[16];
#pragma unroll
        for (int j = 0; j < 16; ++j) {
            int c = __builtin_amdgcn_readfirstlane(col[e + j]);
            u[j] = H[(size_t)c * 64 + lane];
        }
#pragma unroll
        for (int j = 0; j < 16; ++j)
            acc += __uint_as_float((unsigned int)u[j] << 16);
    }
    for (; e + 8 <= e1; e += 8) {
        unsigned short u[8];
#pragma unroll
        for (int j = 0; j < 8; ++j) {
            int c = __builtin_amdgcn_readfirstlane(col[e + j]);
            u[j] = H[(size_t)c * 64 + lane];
        }
#pragma unroll
        for (int j = 0; j < 8; ++j)
            acc += __uint_as_float((unsigned int)u[j] << 16);
    }
    for (; e < e1; ++e) {
        int c = __builtin_amdgcn_readfirstlane(col[e]);
        acc += __uint_as_float((unsigned int)H[(size_t)c * 64 + lane] << 16);
    }
    acc *= di;
    float m = acc;
#pragma unroll
    for (int off = 32; off > 0; off >>= 1)
        m = fmaxf(m, __shfl_xor(m, off, 64));
    float ex = __expf(acc - m);
    float s = ex;
#pragma unroll
    for (int off = 32; off > 0; off >>= 1)
        s += __shfl_xor(s, off, 64);
    out[(size_t)i * 64 + lane] = acc - m - __logf(s);
}

// ---------------------------------------------------------------------------
extern "C" void kernel_launch(void* const* d_in, const int* in_sizes, int n_in,
                              void* d_out, int out_size, void* d_ws, size_t ws_size,
                              hipStream_t stream) {
    const float* x    = (const float*)d_in[0];
    const int*   erow = (const int*)d_in[1];
    const int*   ecol = (const int*)d_in[2];
    const float* W0   = (const float*)d_in[3];
    const float* b0   = (const float*)d_in[4];
    const float* W1   = (const float*)d_in[5];
    const float* b1   = (const float*)d_in[6];
    float* out = (float*)d_out;

    char* ws = (char*)d_ws;
    // layout (bytes):
    //   [0, 512K)            row_ptr (100001 int)
    //   [1M, +25.6M)         h0b  bf16 100000*128   (pre-scaled by dinv[row])
    //   [27M, +25.6M)        h1b  bf16 100000*128
    //   [53M, +12.8M)        h2b  bf16 100000*64    (pre-scaled by dinv[row])
    //   [66M, +32K)          Wt0  bf16 128*128 (as [n][k])
    //   [66.1M, +16K)        Wt1  bf16 64*128  (as [n][k])
    int*             row_ptr = (int*)ws;
    __hip_bfloat16*  h0b     = (__hip_bfloat16*)(ws + (1u << 20));
    __hip_bfloat16*  h1b     = (__hip_bfloat16*)(ws + 27000000u);
    __hip_bfloat16*  h2b     = (__hip_bfloat16*)(ws + 53000000u);
    __hip_bfloat16*  Wt0     = (__hip_bfloat16*)(ws + 66000000u);
    __hip_bfloat16*  Wt1     = (__hip_bfloat16*)(ws + 66100000u);

    // 1. prep: row_ptr + packed weights (one launch)
    prep_kernel<<<NE / 256 + 96, 256, 0, stream>>>(erow, row_ptr, W0, W1, Wt0, Wt1);
    // 2. h0b = bf16(dinv[r] * (x @ W0 + b0))        [MFMA, A from global]
    gemm_mfma<128, float><<<(NN + 127) / 128, 512, 0, stream>>>(x, Wt0, b0, row_ptr, h0b, NN);
    // 3. h1b = bf16(relu(di * sum H[col]))
    spmm_relu_128<<<(NN + 3) / 4, 256, 0, stream>>>(row_ptr, ecol,
                                                    (const unsigned int*)h0b, h1b, NN);
    // 4. h2b = bf16(dinv[r] * (h1b @ W1 + b1))      [MFMA, A from global]
    gemm_mfma<64, __hip_bfloat16><<<(NN + 127) / 128, 512, 0, stream>>>(h1b, Wt1, b1, row_ptr, h2b, NN);
    // 5. out = log_softmax(di * sum H[col])
    spmm_logsoftmax_64<<<(NN + 3) / 4, 256, 0, stream>>>(row_ptr, ecol,
                                                         (const unsigned short*)h2b, out, NN);
}

// Round 9
// 237.656 us; speedup vs baseline: 1.1498x; 1.0064x over previous
//
#include <hip/hip_runtime.h>
#include <hip/hip_bf16.h>

#define NN 100000
#define NE 1600000

typedef __bf16 bf16x8 __attribute__((ext_vector_type(8)));
typedef float  f32x4  __attribute__((ext_vector_type(4)));

// ---------------------------------------------------------------------------
// Fused prep: blocks [0,6250) build CSR row_ptr from sorted edge_row;
// blocks [6250,6346) pack W0/W1 to bf16 [n][k] (B-operand layout).
// ---------------------------------------------------------------------------
__global__ __launch_bounds__(256) void prep_kernel(const int* __restrict__ row,
                                                   int* __restrict__ row_ptr,
                                                   const float* __restrict__ W0,
                                                   const float* __restrict__ W1,
                                                   __hip_bfloat16* __restrict__ Wt0,
                                                   __hip_bfloat16* __restrict__ Wt1) {
    int b = blockIdx.x;
    if (b < NE / 256) {
        int e = b * 256 + threadIdx.x;
        int r  = row[e];
        int rp = (e == 0) ? -1 : row[e - 1];
        for (int i = rp + 1; i <= r; ++i) row_ptr[i] = e;
        if (e == NE - 1) {
            for (int i = r + 1; i <= NN; ++i) row_ptr[i] = NE;
        }
    } else {
        int idx = (b - NE / 256) * 256 + threadIdx.x;
        if (idx < 128 * 128) {
            int n = idx >> 7, k = idx & 127;
            Wt0[idx] = __float2bfloat16(W0[(size_t)k * 128 + n]);
        } else {
            int r2 = idx - 128 * 128;          // < 64*128 by grid size
            int n = r2 >> 7, k = r2 & 127;
            Wt1[r2] = __float2bfloat16(W1[(size_t)k * 64 + n]);
        }
    }
}

__device__ inline float deg_scale(const int* __restrict__ row_ptr, int i) {
    int dg = row_ptr[i + 1] - row_ptr[i];
    return (dg > 0) ? rsqrtf((float)dg) : 0.0f;
}

// ---------------------------------------------------------------------------
// MFMA bf16 GEMM (layer 0): out[M,128] = dinv[r]*(X[M,128] @ Wt^T + bias).
// 512 threads / 8 waves, BM=128 rows. A-fragments direct from global
// (per-lane contiguous 32B, coalesced); W in XOR-swizzled LDS; epilogue via
// wave-local LDS transpose -> coalesced uint4 stores.  (R8-verified)
// Fragment layouts (m89-verified): A[m=lane&15][k=quad*8+j],
// B[n=lane&15][k=quad*8+j], C[row=quad*4+reg][col=lane&15].
// ---------------------------------------------------------------------------
template <int NO, typename InT>
__global__ __launch_bounds__(512) void gemm_mfma(const InT* __restrict__ X,
                                                 const __hip_bfloat16* __restrict__ Wt,
                                                 const float* __restrict__ bias,
                                                 const int* __restrict__ row_ptr,
                                                 __hip_bfloat16* __restrict__ out, int M) {
    constexpr int NT = NO / 16;
    __shared__ unsigned short Ws[NO * 128];
    __shared__ unsigned short Cs[128 * 128];   // epilogue transpose buffer

    const int t = threadIdx.x;
    const int w = t >> 6, lane = t & 63;
    const int l15 = lane & 15, quad = lane >> 4;
    const int rbase = blockIdx.x * 128;

    // stage Wt (NO x 128 bf16) -> Ws, XOR-swizzled granules
    for (int i = t; i < NO * 16; i += 512) {
        int n = i >> 4, g = i & 15;
        *(uint4*)&Ws[n * 128 + ((g ^ (n & 7)) << 3)] = ((const uint4*)Wt)[i];
    }
    __syncthreads();

    const int arow_g = rbase + w * 16 + l15;
    const int arow   = (arow_g < M) ? arow_g : (M - 1);

    bf16x8 af[4];
    if constexpr (sizeof(InT) == 4) {
        float4 lo[4], hi[4];
#pragma unroll
        for (int kc = 0; kc < 4; ++kc) {
            const float4* src = (const float4*)&X[(size_t)arow * 128 + kc * 32 + quad * 8];
            lo[kc] = src[0];
            hi[kc] = src[1];
        }
#pragma unroll
        for (int kc = 0; kc < 4; ++kc) {
            union { bf16x8 v; __hip_bfloat162 h[4]; } u;
            u.h[0] = __float22bfloat162_rn(make_float2(lo[kc].x, lo[kc].y));
            u.h[1] = __float22bfloat162_rn(make_float2(lo[kc].z, lo[kc].w));
            u.h[2] = __float22bfloat162_rn(make_float2(hi[kc].x, hi[kc].y));
            u.h[3] = __float22bfloat162_rn(make_float2(hi[kc].z, hi[kc].w));
            af[kc] = u.v;
        }
    } else {
        union { bf16x8 v; uint4 q; } u[4];
#pragma unroll
        for (int kc = 0; kc < 4; ++kc)
            u[kc].q = *(const uint4*)&X[(size_t)arow * 128 + kc * 32 + quad * 8];
#pragma unroll
        for (int kc = 0; kc < 4; ++kc) af[kc] = u[kc].v;
    }

    f32x4 acc[NT];
#pragma unroll
    for (int nt = 0; nt < NT; ++nt) {
        float bv = bias[nt * 16 + l15];
        acc[nt][0] = bv; acc[nt][1] = bv; acc[nt][2] = bv; acc[nt][3] = bv;
    }

#pragma unroll
    for (int kc = 0; kc < 4; ++kc) {
#pragma unroll
        for (int nt = 0; nt < NT; ++nt) {
            int brow = nt * 16 + l15;
            bf16x8 bfr = *(const bf16x8*)&Ws[brow * 128 + (((kc * 4 + quad) ^ (brow & 7)) << 3)];
            acc[nt] = __builtin_amdgcn_mfma_f32_16x16x32_bf16(af[kc], bfr, acc[nt], 0, 0, 0);
        }
    }

    __hip_bfloat16* Cp = (__hip_bfloat16*)Cs;
#pragma unroll
    for (int r4 = 0; r4 < 4; ++r4) {
        int lrow = w * 16 + quad * 4 + r4;
        int grow = rbase + lrow;
        float sc = (grow < M) ? deg_scale(row_ptr, grow) : 0.f;
#pragma unroll
        for (int nt = 0; nt < NT; ++nt) {
            int ct = nt * 16 + l15;
            Cp[lrow * 128 + ((((ct >> 3) ^ (lrow & 7)) << 3)) + (ct & 7)] =
                __float2bfloat16(acc[nt][r4] * sc);
        }
    }
    constexpr int RJ  = NO / 8;
    constexpr int CNT = (16 * RJ) / 64;
#pragma unroll
    for (int k = 0; k < CNT; ++k) {
        int idx = k * 64 + lane;
        int lr16 = idx / RJ, j = idx % RJ;
        int lrow = w * 16 + lr16;
        int grow = rbase + lrow;
        if (grow < M) {
            uint4 v = *(const uint4*)&Cp[lrow * 128 + ((j ^ (lrow & 7)) << 3)];
            *(uint4*)&out[(size_t)grow * NO + (j << 3)] = v;
        }
    }
}

// ---------------------------------------------------------------------------
// FUSED SpMM+ReLU+GEMM1: per block of 32 rows:
//   phase 1 (gather): wave w computes rows w*4..w*4+4 of
//       h1[i] = relu(dinv[i] * sum_e H[col[e]])  -> 32x128 bf16 LDS tile
//       (XOR-swizzled, exactly the MFMA A-operand layout)
//   phase 2 (MFMA): h2b[32x64] = dinv[r] * (h1_tile @ Wt1^T + b1), direct
//       global stores. Removes the h1 HBM round-trip and the gemm1 launch.
// Grid 3125 * 32 rows == 100000 exactly (no tail). LDS 16KB tile + 16KB Ws.
// ---------------------------------------------------------------------------
__global__ __launch_bounds__(512) void spmm_relu_gemm1(const int* __restrict__ row_ptr,
                                                       const int* __restrict__ col,
                                                       const unsigned int* __restrict__ H, // bf16x2
                                                       const __hip_bfloat16* __restrict__ Wt1,
                                                       const float* __restrict__ b1,
                                                       __hip_bfloat16* __restrict__ out) {
    __shared__ unsigned short As[32 * 128];   // h1 tile (bf16, swizzled)
    __shared__ unsigned short Ws[64 * 128];   // Wt1 (bf16, swizzled)

    const int t = threadIdx.x;
    const int w = t >> 6, lane = t & 63;
    const int l15 = lane & 15, quad = lane >> 4;
    const int rbase = blockIdx.x * 32;

    // stage Wt1 (64 x 128) -> Ws, swizzled
    for (int i = t; i < 64 * 16; i += 512) {
        int n = i >> 4, g = i & 15;
        *(uint4*)&Ws[n * 128 + ((g ^ (n & 7)) << 3)] = ((const uint4*)Wt1)[i];
    }

    // ---- phase 1: gather 4 rows per wave into As ----
    const int gsw = ((lane >> 2) << 3) + ((lane & 3) << 1);  // col granule pos for 2*lane
#pragma unroll 1
    for (int rr = 0; rr < 4; ++rr) {
        const int il = w * 4 + rr;            // local row
        const int i  = rbase + il;            // global row (< NN by exact grid)
        const int e0 = __builtin_amdgcn_readfirstlane(row_ptr[i]);
        const int e1 = __builtin_amdgcn_readfirstlane(row_ptr[i + 1]);
        const int dg = e1 - e0;
        const float di = (dg > 0) ? rsqrtf((float)dg) : 0.0f;
        float accx = 0.f, accy = 0.f;
        int e = e0;
        for (; e + 16 <= e1; e += 16) {
            unsigned int u[16];
#pragma unroll
            for (int j = 0; j < 16; ++j) {
                int c = __builtin_amdgcn_readfirstlane(col[e + j]);
                u[j] = H[(size_t)c * 64 + lane];
            }
#pragma unroll
            for (int j = 0; j < 16; ++j) {
                accx += __uint_as_float(u[j] << 16);
                accy += __uint_as_float(u[j] & 0xffff0000u);
            }
        }
        for (; e + 8 <= e1; e += 8) {
            unsigned int u[8];
#pragma unroll
            for (int j = 0; j < 8; ++j) {
                int c = __builtin_amdgcn_readfirstlane(col[e + j]);
                u[j] = H[(size_t)c * 64 + lane];
            }
#pragma unroll
            for (int j = 0; j < 8; ++j) {
                accx += __uint_as_float(u[j] << 16);
                accy += __uint_as_float(u[j] & 0xffff0000u);
            }
        }
        for (; e < e1; ++e) {
            int c = __builtin_amdgcn_readfirstlane(col[e]);
            unsigned int u = H[(size_t)c * 64 + lane];
            accx += __uint_as_float(u << 16);
            accy += __uint_as_float(u & 0xffff0000u);
        }
        accx = fmaxf(accx * di, 0.f);
        accy = fmaxf(accy * di, 0.f);
        union { __hip_bfloat162 h; unsigned int uu; } p;
        p.h = __float22bfloat162_rn(make_float2(accx, accy));
        // swizzled store: granule (lane>>2)^(il&7), within-granule (lane&3)*2
        *(unsigned int*)&As[il * 128 + ((((lane >> 2) ^ (il & 7)) << 3) + ((lane & 3) << 1))] = p.uu;
    }
    __syncthreads();

    // ---- phase 2: 32x64 = As(32x128) @ Ws^T, wave w does rows (w&1)*16, cols (w>>2? no: w>>1)*16
    const int rb = (w & 1) * 16;     // local row tile
    const int cb = (w >> 1) * 16;    // col tile
    const int arow_l = rb + l15;
    const int asw = arow_l & 7;

    f32x4 acc;
    {
        float bv = b1[cb + l15];
        acc[0] = bv; acc[1] = bv; acc[2] = bv; acc[3] = bv;
    }
#pragma unroll
    for (int kc = 0; kc < 4; ++kc) {
        bf16x8 af = *(const bf16x8*)&As[arow_l * 128 + (((kc * 4 + quad) ^ asw) << 3)];
        int brow = cb + l15;
        bf16x8 bfr = *(const bf16x8*)&Ws[brow * 128 + (((kc * 4 + quad) ^ (brow & 7)) << 3)];
        acc = __builtin_amdgcn_mfma_f32_16x16x32_bf16(af, bfr, acc, 0, 0, 0);
    }

#pragma unroll
    for (int r4 = 0; r4 < 4; ++r4) {
        int grow = rbase + rb + quad * 4 + r4;
        float sc = deg_scale(row_ptr, grow);
        out[(size_t)grow * 64 + cb + l15] = __float2bfloat16(acc[r4] * sc);
    }
}

// ---------------------------------------------------------------------------
// SpMM (CSR, wave-per-row), F=64, bf16 H (pre-scaled), fused log_softmax.
// ---------------------------------------------------------------------------
__global__ __launch_bounds__(256) void spmm_logsoftmax_64(const int* __restrict__ row_ptr,
                                                          const int* __restrict__ col,
                                                          const unsigned short* __restrict__ H, // bf16
                                                          float* __restrict__ out, int N) {
    const int lane = threadIdx.x & 63;
    int i = __builtin_amdgcn_readfirstlane(blockIdx.x * 4 + (threadIdx.x >> 6));
    if (i >= N) return;
    const int e0 = __builtin_amdgcn_readfirstlane(row_ptr[i]);
    const int e1 = __builtin_amdgcn_readfirstlane(row_ptr[i + 1]);
    const int dg = e1 - e0;
    const float di = (dg > 0) ? rsqrtf((float)dg) : 0.0f;
    float acc = 0.f;
    int e = e0;
    for (; e + 16 <= e1; e += 16) {
        unsigned short u[16];
#pragma unroll
        for (int j = 0; j < 16; ++j) {
            int c = __builtin_amdgcn_readfirstlane(col[e + j]);
            u[j] = H[(size_t)c * 64 + lane];
        }
#pragma unroll
        for (int j = 0; j < 16; ++j)
            acc += __uint_as_float((unsigned int)u[j] << 16);
    }
    for (; e + 8 <= e1; e += 8) {
        unsigned short u[8];
#pragma unroll
        for (int j = 0; j < 8; ++j) {
            int c = __builtin_amdgcn_readfirstlane(col[e + j]);
            u[j] = H[(size_t)c * 64 + lane];
        }
#pragma unroll
        for (int j = 0; j < 8; ++j)
            acc += __uint_as_float((unsigned int)u[j] << 16);
    }
    for (; e < e1; ++e) {
        int c = __builtin_amdgcn_readfirstlane(col[e]);
        acc += __uint_as_float((unsigned int)H[(size_t)c * 64 + lane] << 16);
    }
    acc *= di;
    float m = acc;
#pragma unroll
    for (int off = 32; off > 0; off >>= 1)
        m = fmaxf(m, __shfl_xor(m, off, 64));
    float ex = __expf(acc - m);
    float s = ex;
#pragma unroll
    for (int off = 32; off > 0; off >>= 1)
        s += __shfl_xor(s, off, 64);
    out[(size_t)i * 64 + lane] = acc - m - __logf(s);
}

// ---------------------------------------------------------------------------
extern "C" void kernel_launch(void* const* d_in, const int* in_sizes, int n_in,
                              void* d_out, int out_size, void* d_ws, size_t ws_size,
                              hipStream_t stream) {
    const float* x    = (const float*)d_in[0];
    const int*   erow = (const int*)d_in[1];
    const int*   ecol = (const int*)d_in[2];
    const float* W0   = (const float*)d_in[3];
    const float* b0   = (const float*)d_in[4];
    const float* W1   = (const float*)d_in[5];
    const float* b1   = (const float*)d_in[6];
    float* out = (float*)d_out;

    char* ws = (char*)d_ws;
    // layout (bytes):
    //   [0, 512K)            row_ptr (100001 int)
    //   [1M, +25.6M)         h0b  bf16 100000*128   (pre-scaled by dinv[row])
    //   [27M, +12.8M)        h2b  bf16 100000*64    (pre-scaled by dinv[row])
    //   [41M, +32K)          Wt0  bf16 128*128 (as [n][k])
    //   [41.1M, +16K)        Wt1  bf16 64*128  (as [n][k])
    int*             row_ptr = (int*)ws;
    __hip_bfloat16*  h0b     = (__hip_bfloat16*)(ws + (1u << 20));
    __hip_bfloat16*  h2b     = (__hip_bfloat16*)(ws + 27000000u);
    __hip_bfloat16*  Wt0     = (__hip_bfloat16*)(ws + 41000000u);
    __hip_bfloat16*  Wt1     = (__hip_bfloat16*)(ws + 41100000u);

    // 1. prep: row_ptr + packed weights
    prep_kernel<<<NE / 256 + 96, 256, 0, stream>>>(erow, row_ptr, W0, W1, Wt0, Wt1);
    // 2. h0b = bf16(dinv[r] * (x @ W0 + b0))        [MFMA, A from global]
    gemm_mfma<128, float><<<(NN + 127) / 128, 512, 0, stream>>>(x, Wt0, b0, row_ptr, h0b, NN);
    // 3. h2b = bf16(dinv[r] * (relu(spmm(h0b)) @ W1 + b1))   [fused SpMM+GEMM1]
    spmm_relu_gemm1<<<NN / 32, 512, 0, stream>>>(row_ptr, ecol,
                                                 (const unsigned int*)h0b, Wt1, b1, h2b);
    // 4. out = log_softmax(di * sum H[col])
    spmm_logsoftmax_64<<<(NN + 3) / 4, 256, 0, stream>>>(row_ptr, ecol,
                                                         (const unsigned short*)h2b, out, NN);
}

// Round 10
// 228.056 us; speedup vs baseline: 1.1982x; 1.0421x over previous
//
#include <hip/hip_runtime.h>
#include <hip/hip_bf16.h>

#define NN 100000
#define NE 1600000

typedef __bf16 bf16x8 __attribute__((ext_vector_type(8)));
typedef float  f32x4  __attribute__((ext_vector_type(4)));

__device__ inline int rfl(int x) { return __builtin_amdgcn_readfirstlane(x); }

__device__ inline void acc2(float& a, float& b, unsigned int u) {
    a += __uint_as_float(u << 16);
    b += __uint_as_float(u & 0xffff0000u);
}

__device__ inline unsigned int pack_bf2(float x, float y) {
    union { __hip_bfloat162 h; unsigned int u; } p;
    p.h = __float22bfloat162_rn(make_float2(x, y));
    return p.u;
}

// ---------------------------------------------------------------------------
// Fused prep: blocks [0,6250) build CSR row_ptr from sorted edge_row;
// blocks [6250,6346) pack W0/W1 to bf16 [n][k] (B-operand layout).
// ---------------------------------------------------------------------------
__global__ __launch_bounds__(256) void prep_kernel(const int* __restrict__ row,
                                                   int* __restrict__ row_ptr,
                                                   const float* __restrict__ W0,
                                                   const float* __restrict__ W1,
                                                   __hip_bfloat16* __restrict__ Wt0,
                                                   __hip_bfloat16* __restrict__ Wt1) {
    int b = blockIdx.x;
    if (b < NE / 256) {
        int e = b * 256 + threadIdx.x;
        int r  = row[e];
        int rp = (e == 0) ? -1 : row[e - 1];
        for (int i = rp + 1; i <= r; ++i) row_ptr[i] = e;
        if (e == NE - 1) {
            for (int i = r + 1; i <= NN; ++i) row_ptr[i] = NE;
        }
    } else {
        int idx = (b - NE / 256) * 256 + threadIdx.x;
        if (idx < 128 * 128) {
            int n = idx >> 7, k = idx & 127;
            Wt0[idx] = __float2bfloat16(W0[(size_t)k * 128 + n]);
        } else {
            int r2 = idx - 128 * 128;          // < 64*128 by grid size
            int n = r2 >> 7, k = r2 & 127;
            Wt1[r2] = __float2bfloat16(W1[(size_t)k * 64 + n]);
        }
    }
}

__device__ inline float deg_scale(const int* __restrict__ row_ptr, int i) {
    int dg = row_ptr[i + 1] - row_ptr[i];
    return (dg > 0) ? rsqrtf((float)dg) : 0.0f;
}

// ---------------------------------------------------------------------------
// MFMA bf16 GEMM (layer 0): out[M,128] = dinv[r]*(X[M,128] @ Wt^T + bias).
// 512 threads / 8 waves, BM=128 rows. A-fragments direct from global;
// W in XOR-swizzled LDS. Ws and the epilogue transpose buffer now SHARE one
// 32KB LDS allocation (barrier between last Ws read and first Cs write) ->
// higher occupancy (was 64KB -> 2 blocks/CU).
// Fragment layouts (m89-verified): A[m=lane&15][k=quad*8+j],
// B[n=lane&15][k=quad*8+j], C[row=quad*4+reg][col=lane&15].
// ---------------------------------------------------------------------------
template <int NO, typename InT>
__global__ __launch_bounds__(512) void gemm_mfma(const InT* __restrict__ X,
                                                 const __hip_bfloat16* __restrict__ Wt,
                                                 const float* __restrict__ bias,
                                                 const int* __restrict__ row_ptr,
                                                 __hip_bfloat16* __restrict__ out, int M) {
    constexpr int NT = NO / 16;
    __shared__ unsigned short SH[128 * 128];   // Ws role, then Cs role

    const int t = threadIdx.x;
    const int w = t >> 6, lane = t & 63;
    const int l15 = lane & 15, quad = lane >> 4;
    const int rbase = blockIdx.x * 128;

    // stage Wt (NO x 128 bf16) -> SH, XOR-swizzled granules
    for (int i = t; i < NO * 16; i += 512) {
        int n = i >> 4, g = i & 15;
        *(uint4*)&SH[n * 128 + ((g ^ (n & 7)) << 3)] = ((const uint4*)Wt)[i];
    }
    __syncthreads();

    const int arow_g = rbase + w * 16 + l15;
    const int arow   = (arow_g < M) ? arow_g : (M - 1);

    bf16x8 af[4];
    if constexpr (sizeof(InT) == 4) {
        float4 lo[4], hi[4];
#pragma unroll
        for (int kc = 0; kc < 4; ++kc) {
            const float4* src = (const float4*)&X[(size_t)arow * 128 + kc * 32 + quad * 8];
            lo[kc] = src[0];
            hi[kc] = src[1];
        }
#pragma unroll
        for (int kc = 0; kc < 4; ++kc) {
            union { bf16x8 v; __hip_bfloat162 h[4]; } u;
            u.h[0] = __float22bfloat162_rn(make_float2(lo[kc].x, lo[kc].y));
            u.h[1] = __float22bfloat162_rn(make_float2(lo[kc].z, lo[kc].w));
            u.h[2] = __float22bfloat162_rn(make_float2(hi[kc].x, hi[kc].y));
            u.h[3] = __float22bfloat162_rn(make_float2(hi[kc].z, hi[kc].w));
            af[kc] = u.v;
        }
    } else {
        union { bf16x8 v; uint4 q; } u[4];
#pragma unroll
        for (int kc = 0; kc < 4; ++kc)
            u[kc].q = *(const uint4*)&X[(size_t)arow * 128 + kc * 32 + quad * 8];
#pragma unroll
        for (int kc = 0; kc < 4; ++kc) af[kc] = u[kc].v;
    }

    f32x4 acc[NT];
#pragma unroll
    for (int nt = 0; nt < NT; ++nt) {
        float bv = bias[nt * 16 + l15];
        acc[nt][0] = bv; acc[nt][1] = bv; acc[nt][2] = bv; acc[nt][3] = bv;
    }

#pragma unroll
    for (int kc = 0; kc < 4; ++kc) {
#pragma unroll
        for (int nt = 0; nt < NT; ++nt) {
            int brow = nt * 16 + l15;
            bf16x8 bfr = *(const bf16x8*)&SH[brow * 128 + (((kc * 4 + quad) ^ (brow & 7)) << 3)];
            acc[nt] = __builtin_amdgcn_mfma_f32_16x16x32_bf16(af[kc], bfr, acc[nt], 0, 0, 0);
        }
    }
    __syncthreads();   // all waves done reading Ws before SH becomes Cs

    __hip_bfloat16* Cp = (__hip_bfloat16*)SH;
#pragma unroll
    for (int r4 = 0; r4 < 4; ++r4) {
        int lrow = w * 16 + quad * 4 + r4;
        int grow = rbase + lrow;
        float sc = (grow < M) ? deg_scale(row_ptr, grow) : 0.f;
#pragma unroll
        for (int nt = 0; nt < NT; ++nt) {
            int ct = nt * 16 + l15;
            Cp[lrow * 128 + ((((ct >> 3) ^ (lrow & 7)) << 3)) + (ct & 7)] =
                __float2bfloat16(acc[nt][r4] * sc);
        }
    }
    // wave-local RAW on LDS (each wave reads only rows it wrote): no barrier
    constexpr int RJ  = NO / 8;
    constexpr int CNT = (16 * RJ) / 64;
#pragma unroll
    for (int k = 0; k < CNT; ++k) {
        int idx = k * 64 + lane;
        int lr16 = idx / RJ, j = idx % RJ;
        int lrow = w * 16 + lr16;
        int grow = rbase + lrow;
        if (grow < M) {
            uint4 v = *(const uint4*)&Cp[lrow * 128 + ((j ^ (lrow & 7)) << 3)];
            *(uint4*)&out[(size_t)grow * NO + (j << 3)] = v;
        }
    }
}

// ---------------------------------------------------------------------------
// FUSED SpMM+ReLU+GEMM1. Phase 1: 4-edges-per-gather-instruction — lane
// 16p+q loads uint4 (8 features, granule q) of edge e+p; edge slots reduced
// by shfl_xor(16,32); lanes p==0 hold the full row as MFMA granules and
// store straight into the swizzled A-tile. Phase 2: 32x64 MFMA vs Wt1 (LDS),
// dinv-scaled bf16 out. Grid 3125*32 == 100000 exactly.
// ---------------------------------------------------------------------------
__global__ __launch_bounds__(512) void spmm_relu_gemm1(const int* __restrict__ row_ptr,
                                                       const int* __restrict__ col,
                                                       const uint4* __restrict__ H4, // h0b rows = 16 uint4
                                                       const __hip_bfloat16* __restrict__ Wt1,
                                                       const float* __restrict__ b1,
                                                       __hip_bfloat16* __restrict__ out) {
    __shared__ unsigned short As[32 * 128];   // h1 tile (bf16, swizzled)
    __shared__ unsigned short Ws[64 * 128];   // Wt1 (bf16, swizzled)

    const int t = threadIdx.x;
    const int w = t >> 6, lane = t & 63;
    const int l15 = lane & 15, quad = lane >> 4;
    const int rbase = blockIdx.x * 32;
    const int p = lane >> 4;                  // edge slot 0..3
    const int q = lane & 15;                  // feature granule (8 features)

    // stage Wt1 (64 x 128) -> Ws, swizzled
    for (int i = t; i < 64 * 16; i += 512) {
        int n = i >> 4, g = i & 15;
        *(uint4*)&Ws[n * 128 + ((g ^ (n & 7)) << 3)] = ((const uint4*)Wt1)[i];
    }

    // ---- phase 1: gather 4 rows per wave into As, 4 edges per instruction
#pragma unroll 1
    for (int rr = 0; rr < 4; ++rr) {
        const int il = w * 4 + rr;
        const int i  = rbase + il;
        const int e0 = rfl(row_ptr[i]);
        const int e1 = rfl(row_ptr[i + 1]);
        const int dg = e1 - e0;
        const float di = (dg > 0) ? rsqrtf((float)dg) : 0.0f;
        float a0 = 0.f, a1 = 0.f, a2 = 0.f, a3 = 0.f,
              a4 = 0.f, a5 = 0.f, a6 = 0.f, a7 = 0.f;
        int e = e0;
        for (; e + 16 <= e1; e += 16) {       // 4 groups x 4 edges, no clamps
            uint4 v[4];
#pragma unroll
            for (int g2 = 0; g2 < 4; ++g2) {
                int eb = e + g2 * 4;
                int s0 = rfl(col[eb]), s1 = rfl(col[eb + 1]);
                int s2 = rfl(col[eb + 2]), s3 = rfl(col[eb + 3]);
                int c01 = (p & 1) ? s1 : s0;
                int c23 = (p & 1) ? s3 : s2;
                int c   = (p & 2) ? c23 : c01;
                v[g2] = H4[(size_t)c * 16 + q];
            }
#pragma unroll
            for (int g2 = 0; g2 < 4; ++g2) {
                acc2(a0, a1, v[g2].x); acc2(a2, a3, v[g2].y);
                acc2(a4, a5, v[g2].z); acc2(a6, a7, v[g2].w);
            }
        }
        for (; e < e1; e += 4) {              // clamped tail groups
            int em = e1 - 1;
            int j1 = (e + 1 > em) ? em : e + 1;
            int j2 = (e + 2 > em) ? em : e + 2;
            int j3 = (e + 3 > em) ? em : e + 3;
            int s0 = rfl(col[e]),  s1 = rfl(col[j1]);
            int s2 = rfl(col[j2]), s3 = rfl(col[j3]);
            int c01 = (p & 1) ? s1 : s0;
            int c23 = (p & 1) ? s3 : s2;
            int c   = (p & 2) ? c23 : c01;
            uint4 v = H4[(size_t)c * 16 + q];
            if (e + p >= e1) { v.x = 0u; v.y = 0u; v.z = 0u; v.w = 0u; }
            acc2(a0, a1, v.x); acc2(a2, a3, v.y);
            acc2(a4, a5, v.z); acc2(a6, a7, v.w);
        }
        // sum the 4 edge slots
#pragma unroll
        for (int off = 16; off < 64; off <<= 1) {
            a0 += __shfl_xor(a0, off, 64); a1 += __shfl_xor(a1, off, 64);
            a2 += __shfl_xor(a2, off, 64); a3 += __shfl_xor(a3, off, 64);
            a4 += __shfl_xor(a4, off, 64); a5 += __shfl_xor(a5, off, 64);
            a6 += __shfl_xor(a6, off, 64); a7 += __shfl_xor(a7, off, 64);
        }
        if (p == 0) {
            uint4 pk;
            pk.x = pack_bf2(fmaxf(a0 * di, 0.f), fmaxf(a1 * di, 0.f));
            pk.y = pack_bf2(fmaxf(a2 * di, 0.f), fmaxf(a3 * di, 0.f));
            pk.z = pack_bf2(fmaxf(a4 * di, 0.f), fmaxf(a5 * di, 0.f));
            pk.w = pack_bf2(fmaxf(a6 * di, 0.f), fmaxf(a7 * di, 0.f));
            *(uint4*)&As[il * 128 + ((q ^ (il & 7)) << 3)] = pk;
        }
    }
    __syncthreads();

    // ---- phase 2: 32x64 = As(32x128) @ Ws^T
    const int rb = (w & 1) * 16;
    const int cb = (w >> 1) * 16;
    const int arow_l = rb + l15;
    const int asw = arow_l & 7;

    f32x4 acc;
    {
        float bv = b1[cb + l15];
        acc[0] = bv; acc[1] = bv; acc[2] = bv; acc[3] = bv;
    }
#pragma unroll
    for (int kc = 0; kc < 4; ++kc) {
        bf16x8 af = *(const bf16x8*)&As[arow_l * 128 + (((kc * 4 + quad) ^ asw) << 3)];
        int brow = cb + l15;
        bf16x8 bfr = *(const bf16x8*)&Ws[brow * 128 + (((kc * 4 + quad) ^ (brow & 7)) << 3)];
        acc = __builtin_amdgcn_mfma_f32_16x16x32_bf16(af, bfr, acc, 0, 0, 0);
    }

#pragma unroll
    for (int r4 = 0; r4 < 4; ++r4) {
        int grow = rbase + rb + quad * 4 + r4;
        float sc = deg_scale(row_ptr, grow);
        out[(size_t)grow * 64 + cb + l15] = __float2bfloat16(acc[r4] * sc);
    }
}

// ---------------------------------------------------------------------------
// SpMM (CSR, wave-per-row), F=64, fused log_softmax. 8 edges per gather
// instruction: lane 8p+q loads uint4 (8 features) of edge e+p.
// ---------------------------------------------------------------------------
__global__ __launch_bounds__(256) void spmm_logsoftmax_64(const int* __restrict__ row_ptr,
                                                          const int* __restrict__ col,
                                                          const uint4* __restrict__ H4, // h2b rows = 8 uint4
                                                          float* __restrict__ out, int N) {
    const int lane = threadIdx.x & 63;
    const int p = lane >> 3;                  // edge slot 0..7
    const int q = lane & 7;                   // feature granule (8 features)
    int i = rfl(blockIdx.x * 4 + (threadIdx.x >> 6));
    if (i >= N) return;
    const int e0 = rfl(row_ptr[i]);
    const int e1 = rfl(row_ptr[i + 1]);
    const int dg = e1 - e0;
    const float di = (dg > 0) ? rsqrtf((float)dg) : 0.0f;
    float a0 = 0.f, a1 = 0.f, a2 = 0.f, a3 = 0.f,
          a4 = 0.f, a5 = 0.f, a6 = 0.f, a7 = 0.f;
    int e = e0;
    for (; e + 8 <= e1; e += 8) {
        int s0 = rfl(col[e + 0]), s1 = rfl(col[e + 1]);
        int s2 = rfl(col[e + 2]), s3 = rfl(col[e + 3]);
        int s4 = rfl(col[e + 4]), s5 = rfl(col[e + 5]);
        int s6 = rfl(col[e + 6]), s7 = rfl(col[e + 7]);
        int b0 = (p & 1) ? s1 : s0, b1_ = (p & 1) ? s3 : s2;
        int b2 = (p & 1) ? s5 : s4, b3_ = (p & 1) ? s7 : s6;
        int c0 = (p & 2) ? b1_ : b0, c1 = (p & 2) ? b3_ : b2;
        int c  = (p & 4) ? c1 : c0;
        uint4 v = H4[(size_t)c * 8 + q];
        acc2(a0, a1, v.x); acc2(a2, a3, v.y);
        acc2(a4, a5, v.z); acc2(a6, a7, v.w);
    }
    for (; e < e1; e += 8) {                  // one clamped group
        int em = e1 - 1;
        int k1 = (e + 1 > em) ? em : e + 1, k2 = (e + 2 > em) ? em : e + 2;
        int k3 = (e + 3 > em) ? em : e + 3, k4 = (e + 4 > em) ? em : e + 4;
        int k5 = (e + 5 > em) ? em : e + 5, k6 = (e + 6 > em) ? em : e + 6;
        int k7 = (e + 7 > em) ? em : e + 7;
        int s0 = rfl(col[e]),  s1 = rfl(col[k1]);
        int s2 = rfl(col[k2]), s3 = rfl(col[k3]);
        int s4 = rfl(col[k4]), s5 = rfl(col[k5]);
        int s6 = rfl(col[k6]), s7 = rfl(col[k7]);
        int b0 = (p & 1) ? s1 : s0, b1_ = (p & 1) ? s3 : s2;
        int b2 = (p & 1) ? s5 : s4, b3_ = (p & 1) ? s7 : s6;
        int c0 = (p & 2) ? b1_ : b0, c1 = (p & 2) ? b3_ : b2;
        int c  = (p & 4) ? c1 : c0;
        uint4 v = H4[(size_t)c * 8 + q];
        if (e + p >= e1) { v.x = 0u; v.y = 0u; v.z = 0u; v.w = 0u; }
        acc2(a0, a1, v.x); acc2(a2, a3, v.y);
        acc2(a4, a5, v.z); acc2(a6, a7, v.w);
    }
    // sum the 8 edge slots
#pragma unroll
    for (int off = 8; off < 64; off <<= 1) {
        a0 += __shfl_xor(a0, off, 64); a1 += __shfl_xor(a1, off, 64);
        a2 += __shfl_xor(a2, off, 64); a3 += __shfl_xor(a3, off, 64);
        a4 += __shfl_xor(a4, off, 64); a5 += __shfl_xor(a5, off, 64);
        a6 += __shfl_xor(a6, off, 64); a7 += __shfl_xor(a7, off, 64);
    }
    a0 *= di; a1 *= di; a2 *= di; a3 *= di;
    a4 *= di; a5 *= di; a6 *= di; a7 *= di;
    // log_softmax over 64 features (8 per lane x 8 granules)
    float m = fmaxf(fmaxf(fmaxf(a0, a1), fmaxf(a2, a3)),
                    fmaxf(fmaxf(a4, a5), fmaxf(a6, a7)));
#pragma unroll
    for (int off = 1; off < 8; off <<= 1)
        m = fmaxf(m, __shfl_xor(m, off, 64));
    float s = __expf(a0 - m) + __expf(a1 - m) + __expf(a2 - m) + __expf(a3 - m)
            + __expf(a4 - m) + __expf(a5 - m) + __expf(a6 - m) + __expf(a7 - m);
#pragma unroll
    for (int off = 1; off < 8; off <<= 1)
        s += __shfl_xor(s, off, 64);
    float ls = __logf(s);
    if (p == 0) {
        float4 o0 = make_float4(a0 - m - ls, a1 - m - ls, a2 - m - ls, a3 - m - ls);
        float4 o1 = make_float4(a4 - m - ls, a5 - m - ls, a6 - m - ls, a7 - m - ls);
        *(float4*)&out[(size_t)i * 64 + q * 8]     = o0;
        *(float4*)&out[(size_t)i * 64 + q * 8 + 4] = o1;
    }
}

// ---------------------------------------------------------------------------
extern "C" void kernel_launch(void* const* d_in, const int* in_sizes, int n_in,
                              void* d_out, int out_size, void* d_ws, size_t ws_size,
                              hipStream_t stream) {
    const float* x    = (const float*)d_in[0];
    const int*   erow = (const int*)d_in[1];
    const int*   ecol = (const int*)d_in[2];
    const float* W0   = (const float*)d_in[3];
    const float* b0   = (const float*)d_in[4];
    const float* W1   = (const float*)d_in[5];
    const float* b1   = (const float*)d_in[6];
    float* out = (float*)d_out;

    char* ws = (char*)d_ws;
    // layout (bytes):
    //   [0, 512K)            row_ptr (100001 int)
    //   [1M, +25.6M)         h0b  bf16 100000*128   (pre-scaled by dinv[row])
    //   [27M, +12.8M)        h2b  bf16 100000*64    (pre-scaled by dinv[row])
    //   [41M, +32K)          Wt0  bf16 128*128 (as [n][k])
    //   [41.1M, +16K)        Wt1  bf16 64*128  (as [n][k])
    int*             row_ptr = (int*)ws;
    __hip_bfloat16*  h0b     = (__hip_bfloat16*)(ws + (1u << 20));
    __hip_bfloat16*  h2b     = (__hip_bfloat16*)(ws + 27000000u);
    __hip_bfloat16*  Wt0     = (__hip_bfloat16*)(ws + 41000000u);
    __hip_bfloat16*  Wt1     = (__hip_bfloat16*)(ws + 41100000u);

    // 1. prep: row_ptr + packed weights
    prep_kernel<<<NE / 256 + 96, 256, 0, stream>>>(erow, row_ptr, W0, W1, Wt0, Wt1);
    // 2. h0b = bf16(dinv[r] * (x @ W0 + b0))        [MFMA, shared-LDS]
    gemm_mfma<128, float><<<(NN + 127) / 128, 512, 0, stream>>>(x, Wt0, b0, row_ptr, h0b, NN);
    // 3. h2b = bf16(dinv[r] * (relu(spmm(h0b)) @ W1 + b1))   [fused, 4-edge gathers]
    spmm_relu_gemm1<<<NN / 32, 512, 0, stream>>>(row_ptr, ecol,
                                                 (const uint4*)h0b, Wt1, b1, h2b);
    // 4. out = log_softmax(di * sum H[col])                  [8-edge gathers]
    spmm_logsoftmax_64<<<(NN + 3) / 4, 256, 0, stream>>>(row_ptr, ecol,
                                                         (const uint4*)h2b, out, NN);
}